// Round 4
// baseline (2047.209 us; speedup 1.0000x reference)
//
#include <hip/hip_runtime.h>

#define NN 100000
#define NE 3200000

// ===================== CSR build =====================
__global__ __launch_bounds__(256) void count_kernel(const int* __restrict__ dst,
                                                    int* __restrict__ cnt) {
  int stride = gridDim.x * 256;
  for (int e = blockIdx.x * 256 + threadIdx.x; e < NE; e += stride)
    atomicAdd(&cnt[dst[e]], 1);
}

// single-block exclusive scan over NN counts -> rowptr[0..NN]; ofs=running copy
__global__ __launch_bounds__(1024) void scan_kernel(const int* __restrict__ cnt,
                                                    int* __restrict__ rowptr,
                                                    int* __restrict__ ofs) {
  __shared__ int bsum[1024];
  int tid = threadIdx.x;
  const int CH = (NN + 1023) / 1024;
  int lo = tid * CH, hi = lo + CH < NN ? lo + CH : NN;
  if (lo > NN) lo = NN;
  if (hi < lo) hi = lo;
  int s = 0;
  for (int i = lo; i < hi; i++) s += cnt[i];
  bsum[tid] = s;
  __syncthreads();
  for (int off = 1; off < 1024; off <<= 1) {
    int v = bsum[tid];
    int u = (tid >= off) ? bsum[tid - off] : 0;
    __syncthreads();
    bsum[tid] = v + u;
    __syncthreads();
  }
  int pre = (tid == 0) ? 0 : bsum[tid - 1];
  for (int i = lo; i < hi; i++) {
    int cv = cnt[i];
    rowptr[i] = pre;
    ofs[i] = pre;
    pre += cv;
  }
  if (tid == 1023) rowptr[NN] = pre;
}

// rank scatter: perm[pos] = e  (random 4B writes; L2-absorbed)
__global__ __launch_bounds__(256) void scatter1_kernel(
    const int* __restrict__ dst, int* __restrict__ ofs, int* __restrict__ eid_s) {
  int stride = gridDim.x * 256;
  for (int e = blockIdx.x * 256 + threadIdx.x; e < NE; e += stride) {
    int pos = atomicAdd(&ofs[dst[e]], 1);
    eid_s[pos] = e;
  }
}

// pack: gather ea/src via perm (random L3 reads), write records COALESCED.
// pe[i] = [ea0..ea6, src-as-float-bits]; msg1[i] = relu(x[src,:2]+ea@el1w+el1b)
__global__ __launch_bounds__(256) void pack_kernel(
    const int* __restrict__ perm, const int* __restrict__ src,
    const float* __restrict__ ea, const float* __restrict__ x,
    const float* __restrict__ elw, const float* __restrict__ elb,
    float* __restrict__ pe, float* __restrict__ msg1) {
  float w0[7], w1r[7];
#pragma unroll
  for (int k = 0; k < 7; k++) { w0[k] = elw[k * 2]; w1r[k] = elw[k * 2 + 1]; }
  float b0 = elb[0], b1 = elb[1];
  int stride = gridDim.x * 256;
  for (int i = blockIdx.x * 256 + threadIdx.x; i < NE; i += stride) {
    int e = perm[i];
    int sn = src[e];
    float av[7];
#pragma unroll
    for (int k = 0; k < 7; k++) av[k] = ea[e * 7 + k];
    float4 a, b;
    a.x = av[0]; a.y = av[1]; a.z = av[2]; a.w = av[3];
    b.x = av[4]; b.y = av[5]; b.z = av[6];
    b.w = __int_as_float(sn);
    ((float4*)pe)[i * 2 + 0] = a;
    ((float4*)pe)[i * 2 + 1] = b;
    float m0 = b0, m1 = b1;
#pragma unroll
    for (int k = 0; k < 7; k++) {
      m0 = fmaf(av[k], w0[k], m0);
      m1 = fmaf(av[k], w1r[k], m1);
    }
    m0 = fmaxf(m0 + x[sn * 2 + 0], 0.f);
    m1 = fmaxf(m1 + x[sn * 2 + 1], 0.f);
    float2 mv; mv.x = m0; mv.y = m1;
    ((float2*)msg1)[i] = mv;
  }
}

// ============ layer 1 (packed tier): segment-sum of precomputed msg1 =========
__global__ __launch_bounds__(256) void l1sum_kernel(
    const int* __restrict__ rowptr, const float* __restrict__ msg1,
    float* __restrict__ agg) {
  int stride = gridDim.x * 256;
  for (int n = blockIdx.x * 256 + threadIdx.x; n < NN; n += stride) {
    int r0 = rowptr[n], r1 = rowptr[n + 1];
    float a0 = 0.f, a1 = 0.f;
    const float2* mp = (const float2*)msg1;
    for (int i = r0; i < r1; i++) {
      float2 v = mp[i];
      a0 += v.x;
      a1 += v.y;
    }
    agg[n * 2 + 0] = a0;
    agg[n * 2 + 1] = a1;
  }
}

// =========== layer 1 slim-tier aggregate (thread per node, eid CSR) ==========
__global__ __launch_bounds__(256) void l1agg_kernel(
    const int* __restrict__ rowptr, const int* __restrict__ eid_s,
    const int* __restrict__ src, const float* __restrict__ ea,
    const float* __restrict__ x, const float* __restrict__ elw,
    const float* __restrict__ elb, float* __restrict__ agg) {
  float w0[7], w1r[7];
#pragma unroll
  for (int k = 0; k < 7; k++) { w0[k] = elw[k * 2]; w1r[k] = elw[k * 2 + 1]; }
  float b0 = elb[0], b1 = elb[1];
  int stride = gridDim.x * 256;
  for (int n = blockIdx.x * 256 + threadIdx.x; n < NN; n += stride) {
    int r0 = rowptr[n], r1 = rowptr[n + 1];
    float a0 = 0.f, a1 = 0.f;
    for (int i = r0; i < r1; i++) {
      int e = eid_s[i];
      int sn = src[e];
      float m0 = b0, m1 = b1;
#pragma unroll
      for (int k = 0; k < 7; k++) {
        float a = ea[e * 7 + k];
        m0 = fmaf(a, w0[k], m0);
        m1 = fmaf(a, w1r[k], m1);
      }
      m0 = fmaxf(m0 + x[sn * 2 + 0], 0.f);
      m1 = fmaxf(m1 + x[sn * 2 + 1], 0.f);
      a0 += m0; a1 += m1;
    }
    agg[n * 2 + 0] = a0;
    agg[n * 2 + 1] = a1;
  }
}

// ====== layers 2/3 fused, PACKED, 8-deep split-phase gather pipeline =========
__global__ __launch_bounds__(256) void gine64q_kernel(
    const int* __restrict__ rowptr, const float* __restrict__ edat,
    const float* __restrict__ xin, const float* __restrict__ elw,
    const float* __restrict__ elb, const float* __restrict__ w1,
    const float* __restrict__ b1, const float* __restrict__ eps_p,
    float* __restrict__ tbuf, float* __restrict__ stats) {
  __shared__ float wl[64 * 64];
  __shared__ float hb[4][64];
  __shared__ float red[256];
  int tid = threadIdx.x, lane = tid & 63, wv = tid >> 6;
  for (int i = tid; i < 64 * 64; i += 256) wl[i] = w1[i];
  float wel[7];
#pragma unroll
  for (int k = 0; k < 7; k++) wel[k] = elw[k * 64 + lane];
  float bel = elb[lane], b1c = b1[lane];
  float ep = 1.0f + *eps_p;
  float s = 0.f, ss = 0.f;
  __syncthreads();
  const float* pf = edat;
  const float4* p4 = (const float4*)edat;
  const float2* p2 = (const float2*)edat;
  const float* xl = xin + lane;
  int nw = gridDim.x * 4;
  for (int n = blockIdx.x * 4 + wv; n < NN; n += nw) {
    int r0 = rowptr[n], r1 = rowptr[n + 1];
    float acc = 0.f;
    int i = r0;
    // ---- full 8-groups, no masking ----
    while (i + 8 <= r1) {
      int sid[8];
#pragma unroll
      for (int j = 0; j < 8; j++) sid[j] = __float_as_int(pf[(i + j) * 8 + 7]);
      float g[8];
#pragma unroll
      for (int j = 0; j < 8; j++) g[j] = xl[sid[j] * 64];
#pragma unroll
      for (int j = 0; j < 8; j++) {
        float4 a = p4[(i + j) * 2];
        float2 b2 = p2[(i + j) * 4 + 2];
        float c6 = pf[(i + j) * 8 + 6];
        float m = bel;
        m = fmaf(a.x, wel[0], m); m = fmaf(a.y, wel[1], m);
        m = fmaf(a.z, wel[2], m); m = fmaf(a.w, wel[3], m);
        m = fmaf(b2.x, wel[4], m); m = fmaf(b2.y, wel[5], m);
        m = fmaf(c6, wel[6], m);
        acc += fmaxf(m + g[j], 0.f);
      }
      i += 8;
    }
    // ---- masked residual 8-group (reads into slack; clamped gather) ----
    if (i < r1) {
      int cnt = r1 - i;  // 1..7
      int sid[8];
#pragma unroll
      for (int j = 0; j < 8; j++) {
        int raw = __float_as_int(pf[(i + j) * 8 + 7]);
        sid[j] = (j < cnt) ? raw : n;
      }
      float g[8];
#pragma unroll
      for (int j = 0; j < 8; j++) g[j] = xl[sid[j] * 64];
#pragma unroll
      for (int j = 0; j < 8; j++) {
        float4 a = p4[(i + j) * 2];
        float2 b2 = p2[(i + j) * 4 + 2];
        float c6 = pf[(i + j) * 8 + 6];
        float m = bel;
        m = fmaf(a.x, wel[0], m); m = fmaf(a.y, wel[1], m);
        m = fmaf(a.z, wel[2], m); m = fmaf(a.w, wel[3], m);
        m = fmaf(b2.x, wel[4], m); m = fmaf(b2.y, wel[5], m);
        m = fmaf(c6, wel[6], m);
        float v = fmaxf(m + g[j], 0.f);
        acc += (j < cnt) ? v : 0.f;
      }
    }
    float h = ep * xin[n * 64 + lane] + acc;
    hb[wv][lane] = h;  // same-wave LDS exchange (in-order DS pipe)
    float t = b1c;
#pragma unroll
    for (int k = 0; k < 64; k++) t = fmaf(hb[wv][k], wl[k * 64 + lane], t);
    tbuf[n * 64 + lane] = t;
    s += t;
    ss += t * t;
  }
  double* dsum = (double*)stats;
  red[tid] = s;
  __syncthreads();
  if (tid < 64) unsafeAtomicAdd(&dsum[tid], (double)(red[tid] + red[tid + 64] + red[tid + 128] + red[tid + 192]));
  __syncthreads();
  red[tid] = ss;
  __syncthreads();
  if (tid < 64) unsafeAtomicAdd(&dsum[64 + tid], (double)(red[tid] + red[tid + 64] + red[tid + 128] + red[tid + 192]));
}

// ====== layers 2/3 slim-tier (eid CSR, unpipelined — fallback only) ==========
__global__ __launch_bounds__(256) void gine64s_kernel(
    const int* __restrict__ rowptr, const int* __restrict__ eid_s,
    const int* __restrict__ src, const float* __restrict__ ea,
    const float* __restrict__ xin, const float* __restrict__ elw,
    const float* __restrict__ elb, const float* __restrict__ w1,
    const float* __restrict__ b1, const float* __restrict__ eps_p,
    float* __restrict__ tbuf, float* __restrict__ stats) {
  __shared__ float wl[64 * 64];
  __shared__ float hb[4][64];
  __shared__ float red[256];
  int tid = threadIdx.x, lane = tid & 63, wv = tid >> 6;
  for (int i = tid; i < 64 * 64; i += 256) wl[i] = w1[i];
  float wel[7];
#pragma unroll
  for (int k = 0; k < 7; k++) wel[k] = elw[k * 64 + lane];
  float bel = elb[lane], b1c = b1[lane];
  float ep = 1.0f + *eps_p;
  float s = 0.f, ss = 0.f;
  __syncthreads();
  int nw = gridDim.x * 4;
  for (int n = blockIdx.x * 4 + wv; n < NN; n += nw) {
    int r0 = rowptr[n], r1 = rowptr[n + 1];
    float acc = 0.f;
    for (int i = r0; i < r1; i++) {
      int e = eid_s[i];
      int sn = src[e];
      float m = bel;
#pragma unroll
      for (int k = 0; k < 7; k++) m = fmaf(ea[e * 7 + k], wel[k], m);
      m += xin[sn * 64 + lane];
      acc += fmaxf(m, 0.f);
    }
    float h = ep * xin[n * 64 + lane] + acc;
    hb[wv][lane] = h;
    float t = b1c;
#pragma unroll
    for (int k = 0; k < 64; k++) t = fmaf(hb[wv][k], wl[k * 64 + lane], t);
    tbuf[n * 64 + lane] = t;
    s += t;
    ss += t * t;
  }
  double* dsum = (double*)stats;
  red[tid] = s;
  __syncthreads();
  if (tid < 64) unsafeAtomicAdd(&dsum[tid], (double)(red[tid] + red[tid + 64] + red[tid + 128] + red[tid + 192]));
  __syncthreads();
  red[tid] = ss;
  __syncthreads();
  if (tid < 64) unsafeAtomicAdd(&dsum[64 + tid], (double)(red[tid] + red[tid + 64] + red[tid + 128] + red[tid + 192]));
}

// ===================== legacy (fallback tier B) kernels ======================
__global__ __launch_bounds__(256) void edge1_kernel(
    const float* __restrict__ x, const float* __restrict__ ea,
    const int* __restrict__ src, const int* __restrict__ dst,
    const float* __restrict__ elw, const float* __restrict__ elb,
    float* __restrict__ agg) {
  float w0[7], w1[7];
#pragma unroll
  for (int k = 0; k < 7; k++) { w0[k] = elw[k * 2]; w1[k] = elw[k * 2 + 1]; }
  float b0 = elb[0], b1 = elb[1];
  int stride = gridDim.x * 256;
  for (int e = blockIdx.x * 256 + threadIdx.x; e < NE; e += stride) {
    int s = src[e], d = dst[e];
    float m0 = b0, m1 = b1;
#pragma unroll
    for (int k = 0; k < 7; k++) {
      float a = ea[e * 7 + k];
      m0 = fmaf(a, w0[k], m0);
      m1 = fmaf(a, w1[k], m1);
    }
    m0 = fmaxf(m0 + x[s * 2 + 0], 0.f);
    m1 = fmaxf(m1 + x[s * 2 + 1], 0.f);
    unsafeAtomicAdd(&agg[d * 2 + 0], m0);
    unsafeAtomicAdd(&agg[d * 2 + 1], m1);
  }
}

__global__ __launch_bounds__(256) void edge64_kernel(
    const float* __restrict__ xin, const float* __restrict__ ea,
    const int* __restrict__ src, const int* __restrict__ dst,
    const float* __restrict__ elw, const float* __restrict__ elb,
    float* __restrict__ agg) {
  int lane = threadIdx.x & 63;
  int wid = (blockIdx.x * 256 + threadIdx.x) >> 6;
  int nw = (gridDim.x * 256) >> 6;
  float w[7];
#pragma unroll
  for (int k = 0; k < 7; k++) w[k] = elw[k * 64 + lane];
  float b = elb[lane];
  for (int e = wid; e < NE; e += nw) {
    int eu = __builtin_amdgcn_readfirstlane(e);
    int s = src[eu];
    int d = dst[eu];
    float m = b;
#pragma unroll
    for (int k = 0; k < 7; k++) m = fmaf(ea[eu * 7 + k], w[k], m);
    m += xin[s * 64 + lane];
    m = fmaxf(m, 0.f);
    unsafeAtomicAdd(&agg[d * 64 + lane], m);
  }
}

__global__ __launch_bounds__(256) void nodeA64_kernel(
    const float* __restrict__ xin, float* __restrict__ tbuf,
    const float* __restrict__ w1, const float* __restrict__ b1,
    const float* __restrict__ eps_p, float* __restrict__ stats) {
  __shared__ float wl[64 * 64];
  __shared__ float hbuf[4][64];
  __shared__ float red[256];
  int tid = threadIdx.x;
  int c = tid & 63, nl = tid >> 6;
  for (int i = tid; i < 64 * 64; i += 256) wl[i] = w1[i];
  float ep = 1.0f + *eps_p;
  float bc = b1[c];
  float s = 0.f, ss = 0.f;
  __syncthreads();
  for (int n0 = blockIdx.x * 4; n0 < NN; n0 += gridDim.x * 4) {
    int n = n0 + nl;
    bool valid = n < NN;
    float h = 0.f;
    if (valid) h = ep * xin[n * 64 + c] + tbuf[n * 64 + c];
    hbuf[nl][c] = h;
    __syncthreads();
    if (valid) {
      float t = bc;
#pragma unroll
      for (int k = 0; k < 64; k++) t = fmaf(hbuf[nl][k], wl[k * 64 + c], t);
      tbuf[n * 64 + c] = t;
      s += t;
      ss += t * t;
    }
    __syncthreads();
  }
  double* dsum = (double*)stats;
  red[tid] = s;
  __syncthreads();
  if (tid < 64) unsafeAtomicAdd(&dsum[tid], (double)(red[tid] + red[tid + 64] + red[tid + 128] + red[tid + 192]));
  __syncthreads();
  red[tid] = ss;
  __syncthreads();
  if (tid < 64) unsafeAtomicAdd(&dsum[64 + tid], (double)(red[tid] + red[tid + 64] + red[tid + 128] + red[tid + 192]));
}

// ===================== shared node kernels ===================================
__global__ __launch_bounds__(256) void nodeA2_kernel(
    const float* __restrict__ x, const float* __restrict__ agg1,
    float* __restrict__ tbuf, const float* __restrict__ w1,
    const float* __restrict__ b1, const float* __restrict__ eps_p,
    float* __restrict__ stats) {
  __shared__ float red[256];
  int tid = threadIdx.x;
  int c = tid & 63, nl = tid >> 6;
  float wa = w1[c], wb = w1[64 + c], bc = b1[c];
  float ep = 1.0f + *eps_p;
  float s = 0.f, ss = 0.f;
  for (int n0 = blockIdx.x * 4; n0 < NN; n0 += gridDim.x * 4) {
    int n = n0 + nl;
    if (n < NN) {
      float h0 = ep * x[n * 2 + 0] + agg1[n * 2 + 0];
      float h1 = ep * x[n * 2 + 1] + agg1[n * 2 + 1];
      float t = fmaf(h1, wb, fmaf(h0, wa, bc));
      tbuf[n * 64 + c] = t;
      s += t;
      ss += t * t;
    }
  }
  double* dsum = (double*)stats;
  red[tid] = s;
  __syncthreads();
  if (tid < 64) unsafeAtomicAdd(&dsum[tid], (double)(red[tid] + red[tid + 64] + red[tid + 128] + red[tid + 192]));
  __syncthreads();
  red[tid] = ss;
  __syncthreads();
  if (tid < 64) unsafeAtomicAdd(&dsum[64 + tid], (double)(red[tid] + red[tid + 64] + red[tid + 128] + red[tid + 192]));
}

__global__ void statsfin_kernel(float* stats, const float* __restrict__ g,
                                const float* __restrict__ bt) {
  int c = threadIdx.x;  // 64 threads
  const double* ds = (const double*)stats;
  double m = ds[c] / (double)NN;
  double v = ds[64 + c] / (double)NN - m * m;
  float sc = g[c] * (float)(1.0 / sqrt(v + 1e-5));
  stats[256 + c] = sc;
  stats[320 + c] = bt[c] - (float)m * sc;
}

__global__ __launch_bounds__(256) void nodeB_kernel(
    const float* __restrict__ tin, float* __restrict__ outb,
    const float* __restrict__ w2, const float* __restrict__ b2,
    const float* __restrict__ stats) {
  __shared__ float wl[64 * 64];
  __shared__ float ubuf[4][64];
  int tid = threadIdx.x;
  int c = tid & 63, nl = tid >> 6;
  for (int i = tid; i < 64 * 64; i += 256) wl[i] = w2[i];
  float scale = stats[256 + c], shift = stats[320 + c], bc = b2[c];
  __syncthreads();
  for (int n0 = blockIdx.x * 4; n0 < NN; n0 += gridDim.x * 4) {
    int n = n0 + nl;
    bool valid = n < NN;
    float u = 0.f;
    if (valid) {
      float t = tin[n * 64 + c];
      u = fmaxf(fmaf(t, scale, shift), 0.f);
    }
    ubuf[nl][c] = u;
    __syncthreads();
    if (valid) {
      float o = bc;
#pragma unroll
      for (int k = 0; k < 64; k++) o = fmaf(ubuf[nl][k], wl[k * 64 + c], o);
      outb[n * 64 + c] = fmaxf(o, 0.f);
    }
    __syncthreads();
  }
}

__global__ __launch_bounds__(256) void final_kernel(
    const float* __restrict__ xin, const float* __restrict__ regw,
    const float* __restrict__ regb, const float* __restrict__ endw,
    const float* __restrict__ endb, float* __restrict__ out) {
  __shared__ float wl[64 * 128];
  __shared__ float eb[256];
  int tid = threadIdx.x;
  int node = blockIdx.x * 256 + tid;
  bool valid = node < NN;
  float xr[64];
  if (valid) {
    const float4* xp = (const float4*)(xin + node * 64);
#pragma unroll
    for (int k4 = 0; k4 < 16; k4++) {
      float4 v = xp[k4];
      xr[k4 * 4 + 0] = v.x; xr[k4 * 4 + 1] = v.y;
      xr[k4 * 4 + 2] = v.z; xr[k4 * 4 + 3] = v.w;
    }
  }
  float y = 0.f;
  for (int ch = 0; ch < 4; ch++) {
    int j0 = ch * 125;
    __syncthreads();
    for (int idx = tid; idx < 64 * 125; idx += 256) {
      int k = idx / 125;
      int jl = idx - k * 125;
      wl[k * 128 + jl] = regw[k * 500 + j0 + jl];
    }
    if (tid < 125) { eb[tid] = regb[j0 + tid]; eb[128 + tid] = endw[j0 + tid]; }
    __syncthreads();
    if (valid) {
      int jl = 0;
      for (; jl + 4 <= 125; jl += 4) {
        float t0 = eb[jl], t1 = eb[jl + 1], t2 = eb[jl + 2], t3 = eb[jl + 3];
#pragma unroll
        for (int k = 0; k < 64; k++) {
          float4 w4 = *(const float4*)&wl[k * 128 + jl];
          float xv = xr[k];
          t0 = fmaf(xv, w4.x, t0);
          t1 = fmaf(xv, w4.y, t1);
          t2 = fmaf(xv, w4.z, t2);
          t3 = fmaf(xv, w4.w, t3);
        }
        t0 = t0 >= 0.f ? t0 : 0.01f * t0;
        t1 = t1 >= 0.f ? t1 : 0.01f * t1;
        t2 = t2 >= 0.f ? t2 : 0.01f * t2;
        t3 = t3 >= 0.f ? t3 : 0.01f * t3;
        y += t0 * eb[128 + jl] + t1 * eb[128 + jl + 1] + t2 * eb[128 + jl + 2] + t3 * eb[128 + jl + 3];
      }
      {
        float t = eb[124];
#pragma unroll
        for (int k = 0; k < 64; k++) t = fmaf(xr[k], wl[k * 128 + 124], t);
        t = t >= 0.f ? t : 0.01f * t;
        y += t * eb[128 + 124];
      }
    }
  }
  if (valid) out[node] = y + endb[0];
}

extern "C" void kernel_launch(void* const* d_in, const int* in_sizes, int n_in,
                              void* d_out, int out_size, void* d_ws, size_t ws_size,
                              hipStream_t stream) {
  const float* x    = (const float*)d_in[0];
  const float* ea   = (const float*)d_in[1];
  const int*   ei   = (const int*)d_in[2];
  const float* eps1 = (const float*)d_in[4];
  const float* el1w = (const float*)d_in[5];
  const float* el1b = (const float*)d_in[6];
  const float* n1w1 = (const float*)d_in[7];
  const float* n1b1 = (const float*)d_in[8];
  const float* n1g  = (const float*)d_in[9];
  const float* n1bt = (const float*)d_in[10];
  const float* n1w2 = (const float*)d_in[11];
  const float* n1b2 = (const float*)d_in[12];
  const float* eps2 = (const float*)d_in[13];
  const float* el2w = (const float*)d_in[14];
  const float* el2b = (const float*)d_in[15];
  const float* n2w1 = (const float*)d_in[16];
  const float* n2b1 = (const float*)d_in[17];
  const float* n2g  = (const float*)d_in[18];
  const float* n2bt = (const float*)d_in[19];
  const float* n2w2 = (const float*)d_in[20];
  const float* n2b2 = (const float*)d_in[21];
  const float* regw = (const float*)d_in[22];
  const float* regb = (const float*)d_in[23];
  const float* endw = (const float*)d_in[24];
  const float* endb = (const float*)d_in[25];
  const int* srcp = ei;
  const int* dstp = ei + NE;

  // ---- tier-A layout (floats) ----
  const size_t o_stats  = 0;         // 512 floats
  const size_t o_rowptr = 512;       // NN+1 ints
  const size_t o_cnt    = 100516;    // NN ints (scatter offsets)
  const size_t o_buf0   = 200576;    // N*64 floats; msg1 [E,2] pre-layer-2
  const size_t o_buf1   = 6600576;   // N*64 floats; perm [E] ints pre-layer-1
  const size_t o_agg1   = 13000576;  // N*2 floats
  const size_t o_edat   = 13200576;  // packed: E*8 floats + 64 slack | slim: E ints
  const size_t needA2 = (o_edat + (size_t)NE * 8 + 64) * 4;  // ~155.2 MB
  const size_t needA1 = (o_edat + (size_t)NE) * 4;           // ~65.6 MB
  const size_t needB  = (2 * 6600000 + 384) * 4;             // ~52.8 MB

  float* wsf = (float*)d_ws;

  if (ws_size >= needA1) {
    const bool packed = ws_size >= needA2;
    float* stats = wsf + o_stats;
    int* rowptr  = (int*)(wsf + o_rowptr);
    int* cnt     = (int*)(wsf + o_cnt);
    float* buf0  = wsf + o_buf0;
    float* buf1  = wsf + o_buf1;
    float* agg1  = wsf + o_agg1;
    float* edat  = wsf + o_edat;
    float* msg1  = buf0;       // [E,2] == N*64 floats exactly; free until layer 2
    int*   perm  = (int*)buf1; // [E] ints; free until layer-1 nodeA2 writes buf1

    // ---- CSR build (once, shared by all 3 layers) ----
    hipMemsetAsync(cnt, 0, NN * sizeof(int), stream);
    count_kernel<<<4096, 256, 0, stream>>>(dstp, cnt);
    scan_kernel<<<1, 1024, 0, stream>>>(cnt, rowptr, cnt);
    if (packed) {
      scatter1_kernel<<<4096, 256, 0, stream>>>(dstp, cnt, perm);
      pack_kernel<<<4096, 256, 0, stream>>>(perm, srcp, ea, x, el1w, el1b,
                                            edat, msg1);
    } else {
      scatter1_kernel<<<4096, 256, 0, stream>>>(dstp, cnt, (int*)edat);
    }

    // ---- layer 1 ----
    hipMemsetAsync(stats, 0, 128 * sizeof(double), stream);
    if (packed)
      l1sum_kernel<<<391, 256, 0, stream>>>(rowptr, msg1, agg1);
    else
      l1agg_kernel<<<391, 256, 0, stream>>>(rowptr, (const int*)edat, srcp, ea,
                                            x, el1w, el1b, agg1);
    nodeA2_kernel<<<2048, 256, 0, stream>>>(x, agg1, buf1, n1w1, n1b1, eps1, stats);
    statsfin_kernel<<<1, 64, 0, stream>>>(stats, n1g, n1bt);
    nodeB_kernel<<<2048, 256, 0, stream>>>(buf1, buf1, n1w2, n1b2, stats);

    // ---- layers 2,3 (shared weights) ----
    float* cur = buf1;
    float* wrk = buf0;
    for (int l = 0; l < 2; l++) {
      hipMemsetAsync(stats, 0, 128 * sizeof(double), stream);
      if (packed)
        gine64q_kernel<<<4096, 256, 0, stream>>>(rowptr, edat, cur, el2w, el2b,
                                                 n2w1, n2b1, eps2, wrk, stats);
      else
        gine64s_kernel<<<4096, 256, 0, stream>>>(rowptr, (const int*)edat, srcp,
                                                 ea, cur, el2w, el2b, n2w1, n2b1,
                                                 eps2, wrk, stats);
      statsfin_kernel<<<1, 64, 0, stream>>>(stats, n2g, n2bt);
      nodeB_kernel<<<2048, 256, 0, stream>>>(wrk, wrk, n2w2, n2b2, stats);
      float* tmp = cur; cur = wrk; wrk = tmp;
    }

    final_kernel<<<(NN + 255) / 256, 256, 0, stream>>>(cur, regw, regb, endw, endb,
                                                       (float*)d_out);
    return;
  }

  // ================= fallback tier B (round-1 proven path) =================
  if (ws_size < needB) return;
  const size_t BUF = 6600000;
  float* buf0 = (float*)d_ws;
  float* buf1 = buf0 + BUF;
  float* stats = buf1 + BUF;

  float* t1 = buf1;
  float* agg1 = buf1 + NN * 64;
  hipMemsetAsync(agg1, 0, NN * 2 * sizeof(float), stream);
  hipMemsetAsync(stats, 0, 128 * sizeof(double), stream);
  edge1_kernel<<<2048, 256, 0, stream>>>(x, ea, srcp, dstp, el1w, el1b, agg1);
  nodeA2_kernel<<<2048, 256, 0, stream>>>(x, agg1, t1, n1w1, n1b1, eps1, stats);
  statsfin_kernel<<<1, 64, 0, stream>>>(stats, n1g, n1bt);
  nodeB_kernel<<<2048, 256, 0, stream>>>(t1, buf1, n1w2, n1b2, stats);

  float* cur = buf1;
  float* wrk = buf0;
  for (int l = 0; l < 2; l++) {
    hipMemsetAsync(wrk, 0, NN * 64 * sizeof(float), stream);
    hipMemsetAsync(stats, 0, 128 * sizeof(double), stream);
    edge64_kernel<<<2048, 256, 0, stream>>>(cur, ea, srcp, dstp, el2w, el2b, wrk);
    nodeA64_kernel<<<2048, 256, 0, stream>>>(cur, wrk, n2w1, n2b1, eps2, stats);
    statsfin_kernel<<<1, 64, 0, stream>>>(stats, n2g, n2bt);
    nodeB_kernel<<<2048, 256, 0, stream>>>(wrk, wrk, n2w2, n2b2, stats);
    float* tmp = cur; cur = wrk; wrk = tmp;
  }

  final_kernel<<<(NN + 255) / 256, 256, 0, stream>>>(cur, regw, regb, endw, endb,
                                                     (float*)d_out);
}

// Round 5
// 1539.201 us; speedup vs baseline: 1.3300x; 1.3300x over previous
//
#include <hip/hip_runtime.h>

#define NN 100000
#define NE 3200000

// ===================== CSR build =====================
__global__ __launch_bounds__(256) void count_kernel(const int* __restrict__ dst,
                                                    int* __restrict__ cnt) {
  int stride = gridDim.x * 256;
  for (int e = blockIdx.x * 256 + threadIdx.x; e < NE; e += stride)
    atomicAdd(&cnt[dst[e]], 1);
}

// single-block exclusive scan over NN counts -> rowptr[0..NN]; ofs=running copy
__global__ __launch_bounds__(1024) void scan_kernel(const int* __restrict__ cnt,
                                                    int* __restrict__ rowptr,
                                                    int* __restrict__ ofs) {
  __shared__ int bsum[1024];
  int tid = threadIdx.x;
  const int CH = (NN + 1023) / 1024;
  int lo = tid * CH, hi = lo + CH < NN ? lo + CH : NN;
  if (lo > NN) lo = NN;
  if (hi < lo) hi = lo;
  int s = 0;
  for (int i = lo; i < hi; i++) s += cnt[i];
  bsum[tid] = s;
  __syncthreads();
  for (int off = 1; off < 1024; off <<= 1) {
    int v = bsum[tid];
    int u = (tid >= off) ? bsum[tid - off] : 0;
    __syncthreads();
    bsum[tid] = v + u;
    __syncthreads();
  }
  int pre = (tid == 0) ? 0 : bsum[tid - 1];
  for (int i = lo; i < hi; i++) {
    int cv = cnt[i];
    rowptr[i] = pre;
    ofs[i] = pre;
    pre += cv;
  }
  if (tid == 1023) rowptr[NN] = pre;
}

// packed scatter + fused layer-1 message (R3-proven):
//   pe[pos]   = [ea0..ea6, src-as-float-bits]   (32B record)
//   msg1[pos] = relu(x[src,:2] + ea @ el1w + el1b)  ([E,2] sorted)
__global__ __launch_bounds__(256) void scatter2p_kernel(
    const int* __restrict__ src, const int* __restrict__ dst,
    const float* __restrict__ ea, int* __restrict__ ofs,
    float* __restrict__ pe, const float* __restrict__ x,
    const float* __restrict__ elw, const float* __restrict__ elb,
    float* __restrict__ msg1) {
  float w0[7], w1r[7];
#pragma unroll
  for (int k = 0; k < 7; k++) { w0[k] = elw[k * 2]; w1r[k] = elw[k * 2 + 1]; }
  float b0 = elb[0], b1 = elb[1];
  int stride = gridDim.x * 256;
  for (int e = blockIdx.x * 256 + threadIdx.x; e < NE; e += stride) {
    int sn = src[e];
    int pos = atomicAdd(&ofs[dst[e]], 1);
    float av[7];
#pragma unroll
    for (int k = 0; k < 7; k++) av[k] = ea[e * 7 + k];
    float4 a, b;
    a.x = av[0]; a.y = av[1]; a.z = av[2]; a.w = av[3];
    b.x = av[4]; b.y = av[5]; b.z = av[6];
    b.w = __int_as_float(sn);
    ((float4*)pe)[pos * 2 + 0] = a;
    ((float4*)pe)[pos * 2 + 1] = b;
    float m0 = b0, m1 = b1;
#pragma unroll
    for (int k = 0; k < 7; k++) {
      m0 = fmaf(av[k], w0[k], m0);
      m1 = fmaf(av[k], w1r[k], m1);
    }
    m0 = fmaxf(m0 + x[sn * 2 + 0], 0.f);
    m1 = fmaxf(m1 + x[sn * 2 + 1], 0.f);
    float2 mv; mv.x = m0; mv.y = m1;
    ((float2*)msg1)[pos] = mv;
  }
}

// slim scatter: sorted edge ids only
__global__ __launch_bounds__(256) void scatter1_kernel(
    const int* __restrict__ dst, int* __restrict__ ofs, int* __restrict__ eid_s) {
  int stride = gridDim.x * 256;
  for (int e = blockIdx.x * 256 + threadIdx.x; e < NE; e += stride) {
    int pos = atomicAdd(&ofs[dst[e]], 1);
    eid_s[pos] = e;
  }
}

// ============ layer 1 (packed tier): segment-sum of precomputed msg1 =========
__global__ __launch_bounds__(256) void l1sum_kernel(
    const int* __restrict__ rowptr, const float* __restrict__ msg1,
    float* __restrict__ agg) {
  int stride = gridDim.x * 256;
  for (int n = blockIdx.x * 256 + threadIdx.x; n < NN; n += stride) {
    int r0 = rowptr[n], r1 = rowptr[n + 1];
    float a0 = 0.f, a1 = 0.f;
    const float2* mp = (const float2*)msg1;
    for (int i = r0; i < r1; i++) {
      float2 v = mp[i];
      a0 += v.x;
      a1 += v.y;
    }
    agg[n * 2 + 0] = a0;
    agg[n * 2 + 1] = a1;
  }
}

// =========== layer 1 slim-tier aggregate (thread per node, eid CSR) ==========
__global__ __launch_bounds__(256) void l1agg_kernel(
    const int* __restrict__ rowptr, const int* __restrict__ eid_s,
    const int* __restrict__ src, const float* __restrict__ ea,
    const float* __restrict__ x, const float* __restrict__ elw,
    const float* __restrict__ elb, float* __restrict__ agg) {
  float w0[7], w1r[7];
#pragma unroll
  for (int k = 0; k < 7; k++) { w0[k] = elw[k * 2]; w1r[k] = elw[k * 2 + 1]; }
  float b0 = elb[0], b1 = elb[1];
  int stride = gridDim.x * 256;
  for (int n = blockIdx.x * 256 + threadIdx.x; n < NN; n += stride) {
    int r0 = rowptr[n], r1 = rowptr[n + 1];
    float a0 = 0.f, a1 = 0.f;
    for (int i = r0; i < r1; i++) {
      int e = eid_s[i];
      int sn = src[e];
      float m0 = b0, m1 = b1;
#pragma unroll
      for (int k = 0; k < 7; k++) {
        float a = ea[e * 7 + k];
        m0 = fmaf(a, w0[k], m0);
        m1 = fmaf(a, w1r[k], m1);
      }
      m0 = fmaxf(m0 + x[sn * 2 + 0], 0.f);
      m1 = fmaxf(m1 + x[sn * 2 + 1], 0.f);
      a0 += m0; a1 += m1;
    }
    agg[n * 2 + 0] = a0;
    agg[n * 2 + 1] = a1;
  }
}

#define PROJ(m, aq, bq) do { \
  m = bel; \
  m = fmaf((aq).x, wel[0], m); m = fmaf((aq).y, wel[1], m); \
  m = fmaf((aq).z, wel[2], m); m = fmaf((aq).w, wel[3], m); \
  m = fmaf((bq).x, wel[4], m); m = fmaf((bq).y, wel[5], m); \
  m = fmaf((bq).z, wel[6], m); } while (0)

#define LOADG(base) do { \
  na0 = p4[2 * (base) + 0]; nb0 = p4[2 * (base) + 1]; \
  na1 = p4[2 * (base) + 2]; nb1 = p4[2 * (base) + 3]; \
  na2 = p4[2 * (base) + 4]; nb2 = p4[2 * (base) + 5]; \
  na3 = p4[2 * (base) + 6]; nb3 = p4[2 * (base) + 7]; } while (0)

#define CLAMPSID(dst, bq) do { \
  unsigned raw = (unsigned)__float_as_int((bq).w); \
  dst = (raw >= (unsigned)NN) ? 0u : raw; } while (0)

// ====== layers 2/3 fused, PACKED, cross-iteration gather pipeline ============
// Per 4-edge group g (all wave-uniform control):
//   B(g+1): proj + issue gathers from records prefetched last iter
//   A(g+2): prefetch records
//   C(g):   consume gathers issued a full iteration ago (masked)
__global__ __launch_bounds__(256) void gine64r_kernel(
    const int* __restrict__ rowptr, const float* __restrict__ edat,
    const float* __restrict__ xin, const float* __restrict__ elw,
    const float* __restrict__ elb, const float* __restrict__ w1,
    const float* __restrict__ b1, const float* __restrict__ eps_p,
    float* __restrict__ tbuf, float* __restrict__ stats) {
  __shared__ float wl[64 * 64];
  __shared__ float hb[4][64];
  __shared__ float red[256];
  int tid = threadIdx.x, lane = tid & 63, wv = tid >> 6;
  for (int i2 = tid; i2 < 64 * 64; i2 += 256) wl[i2] = w1[i2];
  float wel[7];
#pragma unroll
  for (int k = 0; k < 7; k++) wel[k] = elw[k * 64 + lane];
  float bel = elb[lane], b1c = b1[lane];
  float ep = 1.0f + *eps_p;
  float s = 0.f, ss = 0.f;
  __syncthreads();
  const float4* p4 = (const float4*)edat;
  const float* xl = xin + lane;
  int nw = gridDim.x * 4;
  for (int n = blockIdx.x * 4 + wv; n < NN; n += nw) {
    int r0 = rowptr[n], r1 = rowptr[n + 1];
    int len = r1 - r0;
    float acc = 0.f;
    if (len > 0) {
      int ng = (len + 3) >> 2;
      // --- prologue: records group0 -> mc/gc; records group1 -> na/nb ---
      float4 na0, nb0, na1, nb1, na2, nb2, na3, nb3;
      LOADG(r0);
      float4 ca0 = na0, cb0 = nb0, ca1 = na1, cb1 = nb1;
      float4 ca2 = na2, cb2 = nb2, ca3 = na3, cb3 = nb3;
      int b1i = (ng > 1) ? (r0 + 4) : r0;
      LOADG(b1i);
      float mc0, mc1, mc2, mc3;
      PROJ(mc0, ca0, cb0); PROJ(mc1, ca1, cb1);
      PROJ(mc2, ca2, cb2); PROJ(mc3, ca3, cb3);
      unsigned s0, s1, s2, s3;
      CLAMPSID(s0, cb0); CLAMPSID(s1, cb1); CLAMPSID(s2, cb2); CLAMPSID(s3, cb3);
      float gc0 = xl[s0 * 64], gc1 = xl[s1 * 64];
      float gc2 = xl[s2 * 64], gc3 = xl[s3 * 64];
      for (int g = 0; g < ng; g++) {
        // B(g+1): proj + gathers from na/nb (loaded one iteration ago)
        float mn0, mn1, mn2, mn3;
        PROJ(mn0, na0, nb0); PROJ(mn1, na1, nb1);
        PROJ(mn2, na2, nb2); PROJ(mn3, na3, nb3);
        unsigned t0, t1, t2, t3;
        CLAMPSID(t0, nb0); CLAMPSID(t1, nb1); CLAMPSID(t2, nb2); CLAMPSID(t3, nb3);
        float gn0 = xl[t0 * 64], gn1 = xl[t1 * 64];
        float gn2 = xl[t2 * 64], gn3 = xl[t3 * 64];
        // A(g+2): prefetch records (dummy r0 when out of range)
        int b2 = (g + 2 < ng) ? (r0 + 4 * (g + 2)) : r0;
        LOADG(b2);
        // C(g): consume gathers issued a full iteration ago
        int rem = len - 4 * g;
        acc += (rem > 0) ? fmaxf(mc0 + gc0, 0.f) : 0.f;
        acc += (rem > 1) ? fmaxf(mc1 + gc1, 0.f) : 0.f;
        acc += (rem > 2) ? fmaxf(mc2 + gc2, 0.f) : 0.f;
        acc += (rem > 3) ? fmaxf(mc3 + gc3, 0.f) : 0.f;
        // rotate
        mc0 = mn0; mc1 = mn1; mc2 = mn2; mc3 = mn3;
        gc0 = gn0; gc1 = gn1; gc2 = gn2; gc3 = gn3;
      }
    }
    float h = ep * xin[n * 64 + lane] + acc;
    hb[wv][lane] = h;  // same-wave LDS exchange (in-order DS pipe)
    float t = b1c;
#pragma unroll
    for (int k = 0; k < 64; k++) t = fmaf(hb[wv][k], wl[k * 64 + lane], t);
    tbuf[n * 64 + lane] = t;
    s += t;
    ss += t * t;
  }
  double* dsum = (double*)stats;
  red[tid] = s;
  __syncthreads();
  if (tid < 64) unsafeAtomicAdd(&dsum[tid], (double)(red[tid] + red[tid + 64] + red[tid + 128] + red[tid + 192]));
  __syncthreads();
  red[tid] = ss;
  __syncthreads();
  if (tid < 64) unsafeAtomicAdd(&dsum[64 + tid], (double)(red[tid] + red[tid + 64] + red[tid + 128] + red[tid + 192]));
}

// ====== layers 2/3 slim-tier (eid CSR, unpipelined — fallback only) ==========
__global__ __launch_bounds__(256) void gine64s_kernel(
    const int* __restrict__ rowptr, const int* __restrict__ eid_s,
    const int* __restrict__ src, const float* __restrict__ ea,
    const float* __restrict__ xin, const float* __restrict__ elw,
    const float* __restrict__ elb, const float* __restrict__ w1,
    const float* __restrict__ b1, const float* __restrict__ eps_p,
    float* __restrict__ tbuf, float* __restrict__ stats) {
  __shared__ float wl[64 * 64];
  __shared__ float hb[4][64];
  __shared__ float red[256];
  int tid = threadIdx.x, lane = tid & 63, wv = tid >> 6;
  for (int i = tid; i < 64 * 64; i += 256) wl[i] = w1[i];
  float wel[7];
#pragma unroll
  for (int k = 0; k < 7; k++) wel[k] = elw[k * 64 + lane];
  float bel = elb[lane], b1c = b1[lane];
  float ep = 1.0f + *eps_p;
  float s = 0.f, ss = 0.f;
  __syncthreads();
  int nw = gridDim.x * 4;
  for (int n = blockIdx.x * 4 + wv; n < NN; n += nw) {
    int r0 = rowptr[n], r1 = rowptr[n + 1];
    float acc = 0.f;
    for (int i = r0; i < r1; i++) {
      int e = eid_s[i];
      int sn = src[e];
      float m = bel;
#pragma unroll
      for (int k = 0; k < 7; k++) m = fmaf(ea[e * 7 + k], wel[k], m);
      m += xin[sn * 64 + lane];
      acc += fmaxf(m, 0.f);
    }
    float h = ep * xin[n * 64 + lane] + acc;
    hb[wv][lane] = h;
    float t = b1c;
#pragma unroll
    for (int k = 0; k < 64; k++) t = fmaf(hb[wv][k], wl[k * 64 + lane], t);
    tbuf[n * 64 + lane] = t;
    s += t;
    ss += t * t;
  }
  double* dsum = (double*)stats;
  red[tid] = s;
  __syncthreads();
  if (tid < 64) unsafeAtomicAdd(&dsum[tid], (double)(red[tid] + red[tid + 64] + red[tid + 128] + red[tid + 192]));
  __syncthreads();
  red[tid] = ss;
  __syncthreads();
  if (tid < 64) unsafeAtomicAdd(&dsum[64 + tid], (double)(red[tid] + red[tid + 64] + red[tid + 128] + red[tid + 192]));
}

// ===================== legacy (fallback tier B) kernels ======================
__global__ __launch_bounds__(256) void edge1_kernel(
    const float* __restrict__ x, const float* __restrict__ ea,
    const int* __restrict__ src, const int* __restrict__ dst,
    const float* __restrict__ elw, const float* __restrict__ elb,
    float* __restrict__ agg) {
  float w0[7], w1[7];
#pragma unroll
  for (int k = 0; k < 7; k++) { w0[k] = elw[k * 2]; w1[k] = elw[k * 2 + 1]; }
  float b0 = elb[0], b1 = elb[1];
  int stride = gridDim.x * 256;
  for (int e = blockIdx.x * 256 + threadIdx.x; e < NE; e += stride) {
    int s = src[e], d = dst[e];
    float m0 = b0, m1 = b1;
#pragma unroll
    for (int k = 0; k < 7; k++) {
      float a = ea[e * 7 + k];
      m0 = fmaf(a, w0[k], m0);
      m1 = fmaf(a, w1[k], m1);
    }
    m0 = fmaxf(m0 + x[s * 2 + 0], 0.f);
    m1 = fmaxf(m1 + x[s * 2 + 1], 0.f);
    unsafeAtomicAdd(&agg[d * 2 + 0], m0);
    unsafeAtomicAdd(&agg[d * 2 + 1], m1);
  }
}

__global__ __launch_bounds__(256) void edge64_kernel(
    const float* __restrict__ xin, const float* __restrict__ ea,
    const int* __restrict__ src, const int* __restrict__ dst,
    const float* __restrict__ elw, const float* __restrict__ elb,
    float* __restrict__ agg) {
  int lane = threadIdx.x & 63;
  int wid = (blockIdx.x * 256 + threadIdx.x) >> 6;
  int nw = (gridDim.x * 256) >> 6;
  float w[7];
#pragma unroll
  for (int k = 0; k < 7; k++) w[k] = elw[k * 64 + lane];
  float b = elb[lane];
  for (int e = wid; e < NE; e += nw) {
    int eu = __builtin_amdgcn_readfirstlane(e);
    int s = src[eu];
    int d = dst[eu];
    float m = b;
#pragma unroll
    for (int k = 0; k < 7; k++) m = fmaf(ea[eu * 7 + k], w[k], m);
    m += xin[s * 64 + lane];
    m = fmaxf(m, 0.f);
    unsafeAtomicAdd(&agg[d * 64 + lane], m);
  }
}

__global__ __launch_bounds__(256) void nodeA64_kernel(
    const float* __restrict__ xin, float* __restrict__ tbuf,
    const float* __restrict__ w1, const float* __restrict__ b1,
    const float* __restrict__ eps_p, float* __restrict__ stats) {
  __shared__ float wl[64 * 64];
  __shared__ float hbuf[4][64];
  __shared__ float red[256];
  int tid = threadIdx.x;
  int c = tid & 63, nl = tid >> 6;
  for (int i = tid; i < 64 * 64; i += 256) wl[i] = w1[i];
  float ep = 1.0f + *eps_p;
  float bc = b1[c];
  float s = 0.f, ss = 0.f;
  __syncthreads();
  for (int n0 = blockIdx.x * 4; n0 < NN; n0 += gridDim.x * 4) {
    int n = n0 + nl;
    bool valid = n < NN;
    float h = 0.f;
    if (valid) h = ep * xin[n * 64 + c] + tbuf[n * 64 + c];
    hbuf[nl][c] = h;
    __syncthreads();
    if (valid) {
      float t = bc;
#pragma unroll
      for (int k = 0; k < 64; k++) t = fmaf(hbuf[nl][k], wl[k * 64 + c], t);
      tbuf[n * 64 + c] = t;
      s += t;
      ss += t * t;
    }
    __syncthreads();
  }
  double* dsum = (double*)stats;
  red[tid] = s;
  __syncthreads();
  if (tid < 64) unsafeAtomicAdd(&dsum[tid], (double)(red[tid] + red[tid + 64] + red[tid + 128] + red[tid + 192]));
  __syncthreads();
  red[tid] = ss;
  __syncthreads();
  if (tid < 64) unsafeAtomicAdd(&dsum[64 + tid], (double)(red[tid] + red[tid + 64] + red[tid + 128] + red[tid + 192]));
}

// ===================== shared node kernels ===================================
__global__ __launch_bounds__(256) void nodeA2_kernel(
    const float* __restrict__ x, const float* __restrict__ agg1,
    float* __restrict__ tbuf, const float* __restrict__ w1,
    const float* __restrict__ b1, const float* __restrict__ eps_p,
    float* __restrict__ stats) {
  __shared__ float red[256];
  int tid = threadIdx.x;
  int c = tid & 63, nl = tid >> 6;
  float wa = w1[c], wb = w1[64 + c], bc = b1[c];
  float ep = 1.0f + *eps_p;
  float s = 0.f, ss = 0.f;
  for (int n0 = blockIdx.x * 4; n0 < NN; n0 += gridDim.x * 4) {
    int n = n0 + nl;
    if (n < NN) {
      float h0 = ep * x[n * 2 + 0] + agg1[n * 2 + 0];
      float h1 = ep * x[n * 2 + 1] + agg1[n * 2 + 1];
      float t = fmaf(h1, wb, fmaf(h0, wa, bc));
      tbuf[n * 64 + c] = t;
      s += t;
      ss += t * t;
    }
  }
  double* dsum = (double*)stats;
  red[tid] = s;
  __syncthreads();
  if (tid < 64) unsafeAtomicAdd(&dsum[tid], (double)(red[tid] + red[tid + 64] + red[tid + 128] + red[tid + 192]));
  __syncthreads();
  red[tid] = ss;
  __syncthreads();
  if (tid < 64) unsafeAtomicAdd(&dsum[64 + tid], (double)(red[tid] + red[tid + 64] + red[tid + 128] + red[tid + 192]));
}

// ------------- node B with fused BN finalize: u=relu(BN(t)); out=relu(u@w2+b2)
__global__ __launch_bounds__(256) void nodeB_kernel(
    const float* __restrict__ tin, float* __restrict__ outb,
    const float* __restrict__ w2, const float* __restrict__ b2,
    const float* __restrict__ stats, const float* __restrict__ g,
    const float* __restrict__ bt) {
  __shared__ float wl[64 * 64];
  __shared__ float ubuf[4][64];
  __shared__ float scsh[128];
  int tid = threadIdx.x;
  int c = tid & 63, nl = tid >> 6;
  for (int i = tid; i < 64 * 64; i += 256) wl[i] = w2[i];
  if (tid < 64) {
    const double* ds = (const double*)stats;
    double m = ds[tid] / (double)NN;
    double v = ds[64 + tid] / (double)NN - m * m;
    float sc = g[tid] * (float)(1.0 / sqrt(v + 1e-5));
    scsh[tid] = sc;
    scsh[64 + tid] = bt[tid] - (float)m * sc;
  }
  float bc = b2[c];
  __syncthreads();
  float scale = scsh[c], shift = scsh[64 + c];
  for (int n0 = blockIdx.x * 4; n0 < NN; n0 += gridDim.x * 4) {
    int n = n0 + nl;
    bool valid = n < NN;
    float u = 0.f;
    if (valid) {
      float t = tin[n * 64 + c];
      u = fmaxf(fmaf(t, scale, shift), 0.f);
    }
    ubuf[nl][c] = u;
    __syncthreads();
    if (valid) {
      float o = bc;
#pragma unroll
      for (int k = 0; k < 64; k++) o = fmaf(ubuf[nl][k], wl[k * 64 + c], o);
      outb[n * 64 + c] = fmaxf(o, 0.f);
    }
    __syncthreads();
  }
}

__global__ __launch_bounds__(256) void final_kernel(
    const float* __restrict__ xin, const float* __restrict__ regw,
    const float* __restrict__ regb, const float* __restrict__ endw,
    const float* __restrict__ endb, float* __restrict__ out) {
  __shared__ float wl[64 * 128];
  __shared__ float eb[256];
  int tid = threadIdx.x;
  int node = blockIdx.x * 256 + tid;
  bool valid = node < NN;
  float xr[64];
  if (valid) {
    const float4* xp = (const float4*)(xin + node * 64);
#pragma unroll
    for (int k4 = 0; k4 < 16; k4++) {
      float4 v = xp[k4];
      xr[k4 * 4 + 0] = v.x; xr[k4 * 4 + 1] = v.y;
      xr[k4 * 4 + 2] = v.z; xr[k4 * 4 + 3] = v.w;
    }
  }
  float y = 0.f;
  for (int ch = 0; ch < 4; ch++) {
    int j0 = ch * 125;
    __syncthreads();
    for (int idx = tid; idx < 64 * 125; idx += 256) {
      int k = idx / 125;
      int jl = idx - k * 125;
      wl[k * 128 + jl] = regw[k * 500 + j0 + jl];
    }
    if (tid < 125) { eb[tid] = regb[j0 + tid]; eb[128 + tid] = endw[j0 + tid]; }
    __syncthreads();
    if (valid) {
      int jl = 0;
      for (; jl + 4 <= 125; jl += 4) {
        float t0 = eb[jl], t1 = eb[jl + 1], t2 = eb[jl + 2], t3 = eb[jl + 3];
#pragma unroll
        for (int k = 0; k < 64; k++) {
          float4 w4 = *(const float4*)&wl[k * 128 + jl];
          float xv = xr[k];
          t0 = fmaf(xv, w4.x, t0);
          t1 = fmaf(xv, w4.y, t1);
          t2 = fmaf(xv, w4.z, t2);
          t3 = fmaf(xv, w4.w, t3);
        }
        t0 = t0 >= 0.f ? t0 : 0.01f * t0;
        t1 = t1 >= 0.f ? t1 : 0.01f * t1;
        t2 = t2 >= 0.f ? t2 : 0.01f * t2;
        t3 = t3 >= 0.f ? t3 : 0.01f * t3;
        y += t0 * eb[128 + jl] + t1 * eb[128 + jl + 1] + t2 * eb[128 + jl + 2] + t3 * eb[128 + jl + 3];
      }
      {
        float t = eb[124];
#pragma unroll
        for (int k = 0; k < 64; k++) t = fmaf(xr[k], wl[k * 128 + 124], t);
        t = t >= 0.f ? t : 0.01f * t;
        y += t * eb[128 + 124];
      }
    }
  }
  if (valid) out[node] = y + endb[0];
}

extern "C" void kernel_launch(void* const* d_in, const int* in_sizes, int n_in,
                              void* d_out, int out_size, void* d_ws, size_t ws_size,
                              hipStream_t stream) {
  const float* x    = (const float*)d_in[0];
  const float* ea   = (const float*)d_in[1];
  const int*   ei   = (const int*)d_in[2];
  const float* eps1 = (const float*)d_in[4];
  const float* el1w = (const float*)d_in[5];
  const float* el1b = (const float*)d_in[6];
  const float* n1w1 = (const float*)d_in[7];
  const float* n1b1 = (const float*)d_in[8];
  const float* n1g  = (const float*)d_in[9];
  const float* n1bt = (const float*)d_in[10];
  const float* n1w2 = (const float*)d_in[11];
  const float* n1b2 = (const float*)d_in[12];
  const float* eps2 = (const float*)d_in[13];
  const float* el2w = (const float*)d_in[14];
  const float* el2b = (const float*)d_in[15];
  const float* n2w1 = (const float*)d_in[16];
  const float* n2b1 = (const float*)d_in[17];
  const float* n2g  = (const float*)d_in[18];
  const float* n2bt = (const float*)d_in[19];
  const float* n2w2 = (const float*)d_in[20];
  const float* n2b2 = (const float*)d_in[21];
  const float* regw = (const float*)d_in[22];
  const float* regb = (const float*)d_in[23];
  const float* endw = (const float*)d_in[24];
  const float* endb = (const float*)d_in[25];
  const int* srcp = ei;
  const int* dstp = ei + NE;

  // ---- tier-A layout (floats) ----
  const size_t o_stats  = 0;         // 512 floats
  const size_t o_rowptr = 512;       // NN+1 ints
  const size_t o_cnt    = 100516;    // NN ints (scatter offsets)
  const size_t o_buf0   = 200576;    // N*64 floats; msg1 [E,2] pre-layer-2
  const size_t o_buf1   = 6600576;   // N*64 floats
  const size_t o_agg1   = 13000576;  // N*2 floats
  const size_t o_edat   = 13200576;  // packed: E*8 floats + 96 slack | slim: E ints
  const size_t needA2 = (o_edat + (size_t)NE * 8 + 96) * 4;  // ~155.2 MB
  const size_t needA1 = (o_edat + (size_t)NE) * 4;           // ~65.6 MB
  const size_t needB  = (2 * 6600000 + 384) * 4;             // ~52.8 MB

  float* wsf = (float*)d_ws;

  if (ws_size >= needA1) {
    const bool packed = ws_size >= needA2;
    float* stats = wsf + o_stats;
    int* rowptr  = (int*)(wsf + o_rowptr);
    int* cnt     = (int*)(wsf + o_cnt);
    float* buf0  = wsf + o_buf0;
    float* buf1  = wsf + o_buf1;
    float* agg1  = wsf + o_agg1;
    float* edat  = wsf + o_edat;
    float* msg1  = buf0;  // [E,2] == N*64 floats exactly; free until layer 2

    // ---- CSR build (once, shared by all 3 layers) ----
    hipMemsetAsync(cnt, 0, NN * sizeof(int), stream);
    count_kernel<<<4096, 256, 0, stream>>>(dstp, cnt);
    scan_kernel<<<1, 1024, 0, stream>>>(cnt, rowptr, cnt);
    if (packed)
      scatter2p_kernel<<<4096, 256, 0, stream>>>(srcp, dstp, ea, cnt, edat,
                                                 x, el1w, el1b, msg1);
    else
      scatter1_kernel<<<4096, 256, 0, stream>>>(dstp, cnt, (int*)edat);

    // ---- layer 1 ----
    hipMemsetAsync(stats, 0, 128 * sizeof(double), stream);
    if (packed)
      l1sum_kernel<<<391, 256, 0, stream>>>(rowptr, msg1, agg1);
    else
      l1agg_kernel<<<391, 256, 0, stream>>>(rowptr, (const int*)edat, srcp, ea,
                                            x, el1w, el1b, agg1);
    nodeA2_kernel<<<2048, 256, 0, stream>>>(x, agg1, buf1, n1w1, n1b1, eps1, stats);
    nodeB_kernel<<<2048, 256, 0, stream>>>(buf1, buf1, n1w2, n1b2, stats, n1g, n1bt);

    // ---- layers 2,3 (shared weights) ----
    float* cur = buf1;
    float* wrk = buf0;
    for (int l = 0; l < 2; l++) {
      hipMemsetAsync(stats, 0, 128 * sizeof(double), stream);
      if (packed)
        gine64r_kernel<<<4096, 256, 0, stream>>>(rowptr, edat, cur, el2w, el2b,
                                                 n2w1, n2b1, eps2, wrk, stats);
      else
        gine64s_kernel<<<4096, 256, 0, stream>>>(rowptr, (const int*)edat, srcp,
                                                 ea, cur, el2w, el2b, n2w1, n2b1,
                                                 eps2, wrk, stats);
      nodeB_kernel<<<2048, 256, 0, stream>>>(wrk, wrk, n2w2, n2b2, stats, n2g, n2bt);
      float* tmp = cur; cur = wrk; wrk = tmp;
    }

    final_kernel<<<(NN + 255) / 256, 256, 0, stream>>>(cur, regw, regb, endw, endb,
                                                       (float*)d_out);
    return;
  }

  // ================= fallback tier B (round-1 proven path) =================
  if (ws_size < needB) return;
  const size_t BUF = 6600000;
  float* buf0 = (float*)d_ws;
  float* buf1 = buf0 + BUF;
  float* stats = buf1 + BUF;

  float* t1 = buf1;
  float* agg1 = buf1 + NN * 64;
  hipMemsetAsync(agg1, 0, NN * 2 * sizeof(float), stream);
  hipMemsetAsync(stats, 0, 128 * sizeof(double), stream);
  edge1_kernel<<<2048, 256, 0, stream>>>(x, ea, srcp, dstp, el1w, el1b, agg1);
  nodeA2_kernel<<<2048, 256, 0, stream>>>(x, agg1, t1, n1w1, n1b1, eps1, stats);
  nodeB_kernel<<<2048, 256, 0, stream>>>(t1, buf1, n1w2, n1b2, stats, n1g, n1bt);

  float* cur = buf1;
  float* wrk = buf0;
  for (int l = 0; l < 2; l++) {
    hipMemsetAsync(wrk, 0, NN * 64 * sizeof(float), stream);
    hipMemsetAsync(stats, 0, 128 * sizeof(double), stream);
    edge64_kernel<<<2048, 256, 0, stream>>>(cur, ea, srcp, dstp, el2w, el2b, wrk);
    nodeA64_kernel<<<2048, 256, 0, stream>>>(cur, wrk, n2w1, n2b1, eps2, stats);
    nodeB_kernel<<<2048, 256, 0, stream>>>(wrk, wrk, n2w2, n2b2, stats, n2g, n2bt);
    float* tmp = cur; cur = wrk; wrk = tmp;
  }

  final_kernel<<<(NN + 255) / 256, 256, 0, stream>>>(cur, regw, regb, endw, endb,
                                                     (float*)d_out);
}

// Round 6
// 1347.898 us; speedup vs baseline: 1.5188x; 1.1419x over previous
//
#include <hip/hip_runtime.h>
#include <hip/hip_fp16.h>

#define NN 100000
#define NE 3200000

// ---------- fp16 pack/unpack helpers ----------
__device__ inline unsigned pkh(float a, float b) {
  __half2 h;
  h.x = __float2half(a);
  h.y = __float2half(b);
  unsigned u;
  __builtin_memcpy(&u, &h, 4);
  return u;
}
__device__ inline float2 uph(unsigned u) {
  __half2 h;
  __builtin_memcpy(&h, &u, 4);
  return __half22float2(h);
}
__device__ inline float h1f(unsigned short v) {
  __half h;
  __builtin_memcpy(&h, &v, 2);
  return __half2float(h);
}
__device__ inline unsigned short f1h(float f) {
  __half h = __float2half(f);
  unsigned short u;
  __builtin_memcpy(&u, &h, 2);
  return u;
}

// ===================== CSR build =====================
__global__ __launch_bounds__(256) void count_kernel(const int* __restrict__ dst,
                                                    int* __restrict__ cnt) {
  int stride = gridDim.x * 256;
  for (int e = blockIdx.x * 256 + threadIdx.x; e < NE; e += stride)
    atomicAdd(&cnt[dst[e]], 1);
}

// single-block exclusive scan over NN counts -> rowptr[0..NN]; ofs=running copy
__global__ __launch_bounds__(1024) void scan_kernel(const int* __restrict__ cnt,
                                                    int* __restrict__ rowptr,
                                                    int* __restrict__ ofs) {
  __shared__ int bsum[1024];
  int tid = threadIdx.x;
  const int CH = (NN + 1023) / 1024;
  int lo = tid * CH, hi = lo + CH < NN ? lo + CH : NN;
  if (lo > NN) lo = NN;
  if (hi < lo) hi = lo;
  int s = 0;
  for (int i = lo; i < hi; i++) s += cnt[i];
  bsum[tid] = s;
  __syncthreads();
  for (int off = 1; off < 1024; off <<= 1) {
    int v = bsum[tid];
    int u = (tid >= off) ? bsum[tid - off] : 0;
    __syncthreads();
    bsum[tid] = v + u;
    __syncthreads();
  }
  int pre = (tid == 0) ? 0 : bsum[tid - 1];
  for (int i = lo; i < hi; i++) {
    int cv = cnt[i];
    rowptr[i] = pre;
    ofs[i] = pre;
    pre += cv;
  }
  if (tid == 1023) rowptr[NN] = pre;
}

// packed fp16 scatter + fused layer-1 message:
//   erec[pos] = uint4 of 7×fp16 ea (+pad)   (16B record)
//   esrc[pos] = src                          (4B)
//   msg1[pos] = relu(x[src,:2] + ea@el1w + el1b) as float2
__global__ __launch_bounds__(256) void scatter2h_kernel(
    const int* __restrict__ src, const int* __restrict__ dst,
    const float* __restrict__ ea, int* __restrict__ ofs,
    uint4* __restrict__ erec, int* __restrict__ esrc,
    const float* __restrict__ x, const float* __restrict__ elw,
    const float* __restrict__ elb, float* __restrict__ msg1) {
  float w0[7], w1r[7];
#pragma unroll
  for (int k = 0; k < 7; k++) { w0[k] = elw[k * 2]; w1r[k] = elw[k * 2 + 1]; }
  float b0 = elb[0], b1 = elb[1];
  int stride = gridDim.x * 256;
  for (int e = blockIdx.x * 256 + threadIdx.x; e < NE; e += stride) {
    int sn = src[e];
    int pos = atomicAdd(&ofs[dst[e]], 1);
    float av[7];
#pragma unroll
    for (int k = 0; k < 7; k++) av[k] = ea[e * 7 + k];
    uint4 r;
    r.x = pkh(av[0], av[1]);
    r.y = pkh(av[2], av[3]);
    r.z = pkh(av[4], av[5]);
    r.w = pkh(av[6], 0.f);
    erec[pos] = r;
    esrc[pos] = sn;
    float m0 = b0, m1 = b1;
#pragma unroll
    for (int k = 0; k < 7; k++) {
      m0 = fmaf(av[k], w0[k], m0);
      m1 = fmaf(av[k], w1r[k], m1);
    }
    m0 = fmaxf(m0 + x[sn * 2 + 0], 0.f);
    m1 = fmaxf(m1 + x[sn * 2 + 1], 0.f);
    float2 mv; mv.x = m0; mv.y = m1;
    ((float2*)msg1)[pos] = mv;
  }
}

// slim scatter: sorted edge ids only
__global__ __launch_bounds__(256) void scatter1_kernel(
    const int* __restrict__ dst, int* __restrict__ ofs, int* __restrict__ eid_s) {
  int stride = gridDim.x * 256;
  for (int e = blockIdx.x * 256 + threadIdx.x; e < NE; e += stride) {
    int pos = atomicAdd(&ofs[dst[e]], 1);
    eid_s[pos] = e;
  }
}

// ============ layer 1 (packed tier): segment-sum of precomputed msg1 =========
__global__ __launch_bounds__(256) void l1sum_kernel(
    const int* __restrict__ rowptr, const float* __restrict__ msg1,
    float* __restrict__ agg) {
  int stride = gridDim.x * 256;
  for (int n = blockIdx.x * 256 + threadIdx.x; n < NN; n += stride) {
    int r0 = rowptr[n], r1 = rowptr[n + 1];
    float a0 = 0.f, a1 = 0.f;
    const float2* mp = (const float2*)msg1;
    for (int i = r0; i < r1; i++) {
      float2 v = mp[i];
      a0 += v.x;
      a1 += v.y;
    }
    agg[n * 2 + 0] = a0;
    agg[n * 2 + 1] = a1;
  }
}

// =========== layer 1 slim-tier aggregate (thread per node, eid CSR) ==========
__global__ __launch_bounds__(256) void l1agg_kernel(
    const int* __restrict__ rowptr, const int* __restrict__ eid_s,
    const int* __restrict__ src, const float* __restrict__ ea,
    const float* __restrict__ x, const float* __restrict__ elw,
    const float* __restrict__ elb, float* __restrict__ agg) {
  float w0[7], w1r[7];
#pragma unroll
  for (int k = 0; k < 7; k++) { w0[k] = elw[k * 2]; w1r[k] = elw[k * 2 + 1]; }
  float b0 = elb[0], b1 = elb[1];
  int stride = gridDim.x * 256;
  for (int n = blockIdx.x * 256 + threadIdx.x; n < NN; n += stride) {
    int r0 = rowptr[n], r1 = rowptr[n + 1];
    float a0 = 0.f, a1 = 0.f;
    for (int i = r0; i < r1; i++) {
      int e = eid_s[i];
      int sn = src[e];
      float m0 = b0, m1 = b1;
#pragma unroll
      for (int k = 0; k < 7; k++) {
        float a = ea[e * 7 + k];
        m0 = fmaf(a, w0[k], m0);
        m1 = fmaf(a, w1r[k], m1);
      }
      m0 = fmaxf(m0 + x[sn * 2 + 0], 0.f);
      m1 = fmaxf(m1 + x[sn * 2 + 1], 0.f);
      a0 += m0; a1 += m1;
    }
    agg[n * 2 + 0] = a0;
    agg[n * 2 + 1] = a1;
  }
}

#define PROJH(m, u) do { \
  float2 q0 = uph((u).x), q1 = uph((u).y), q2 = uph((u).z), q3 = uph((u).w); \
  m = bel; \
  m = fmaf(q0.x, wel[0], m); m = fmaf(q0.y, wel[1], m); \
  m = fmaf(q1.x, wel[2], m); m = fmaf(q1.y, wel[3], m); \
  m = fmaf(q2.x, wel[4], m); m = fmaf(q2.y, wel[5], m); \
  m = fmaf(q3.x, wel[6], m); } while (0)

// ====== layers 2/3 fused, fp16 records + fp16 gathers, 4-deep pipeline =======
__global__ __launch_bounds__(256) void gine64h_kernel(
    const int* __restrict__ rowptr, const uint4* __restrict__ erec,
    const int* __restrict__ esrc, const float* __restrict__ xin,
    const unsigned short* __restrict__ xh, const float* __restrict__ elw,
    const float* __restrict__ elb, const float* __restrict__ w1,
    const float* __restrict__ b1, const float* __restrict__ eps_p,
    float* __restrict__ tbuf, float* __restrict__ stats) {
  __shared__ float wl[64 * 64];
  __shared__ float hb[4][64];
  __shared__ float red[256];
  int tid = threadIdx.x, lane = tid & 63, wv = tid >> 6;
  for (int i2 = tid; i2 < 64 * 64; i2 += 256) wl[i2] = w1[i2];
  float wel[7];
#pragma unroll
  for (int k = 0; k < 7; k++) wel[k] = elw[k * 64 + lane];
  float bel = elb[lane], b1c = b1[lane];
  float ep = 1.0f + *eps_p;
  float s = 0.f, ss = 0.f;
  __syncthreads();
  const unsigned short* xl = xh + lane;
  int nw = gridDim.x * 4;
  for (int n = blockIdx.x * 4 + wv; n < NN; n += nw) {
    int r0 = rowptr[n], r1 = rowptr[n + 1];
    float acc = 0.f;
    int i = r0;
    int rem = r1 - r0;
    if (rem >= 4) {
      uint4 u0 = erec[i], u1 = erec[i + 1], u2 = erec[i + 2], u3 = erec[i + 3];
      int s0 = esrc[i], s1 = esrc[i + 1], s2 = esrc[i + 2], s3 = esrc[i + 3];
      while (true) {
        // issue 4 independent fp16 gathers (one cache line each)
        float g0 = h1f(xl[s0 * 64]);
        float g1 = h1f(xl[s1 * 64]);
        float g2 = h1f(xl[s2 * 64]);
        float g3 = h1f(xl[s3 * 64]);
        i += 4; rem -= 4;
        bool more = rem >= 4;
        int ip = more ? i : r0;  // dummy (valid) address when finishing
        // prefetch next group's records/srcs while gathers are in flight
        uint4 v0 = erec[ip], v1 = erec[ip + 1], v2 = erec[ip + 2], v3 = erec[ip + 3];
        int t0 = esrc[ip], t1 = esrc[ip + 1], t2 = esrc[ip + 2], t3 = esrc[ip + 3];
        // edge projections (independent of gathers)
        float m0, m1, m2, m3;
        PROJH(m0, u0); PROJH(m1, u1); PROJH(m2, u2); PROJH(m3, u3);
        acc += fmaxf(m0 + g0, 0.f);
        acc += fmaxf(m1 + g1, 0.f);
        acc += fmaxf(m2 + g2, 0.f);
        acc += fmaxf(m3 + g3, 0.f);
        u0 = v0; u1 = v1; u2 = v2; u3 = v3;
        s0 = t0; s1 = t1; s2 = t2; s3 = t3;
        if (!more) break;
      }
    }
    for (; i < r1; i++) {  // tail (0..3 edges)
      uint4 u = erec[i];
      int sn = esrc[i];
      float m;
      PROJH(m, u);
      m += h1f(xl[sn * 64]);
      acc += fmaxf(m, 0.f);
    }
    float h = ep * xin[n * 64 + lane] + acc;
    hb[wv][lane] = h;  // same-wave LDS exchange (in-order DS pipe)
    float t = b1c;
#pragma unroll
    for (int k = 0; k < 64; k++) t = fmaf(hb[wv][k], wl[k * 64 + lane], t);
    tbuf[n * 64 + lane] = t;
    s += t;
    ss += t * t;
  }
  double* dsum = (double*)stats;
  red[tid] = s;
  __syncthreads();
  if (tid < 64) unsafeAtomicAdd(&dsum[tid], (double)(red[tid] + red[tid + 64] + red[tid + 128] + red[tid + 192]));
  __syncthreads();
  red[tid] = ss;
  __syncthreads();
  if (tid < 64) unsafeAtomicAdd(&dsum[64 + tid], (double)(red[tid] + red[tid + 64] + red[tid + 128] + red[tid + 192]));
}

// ====== layers 2/3 slim-tier (eid CSR, unpipelined — fallback only) ==========
__global__ __launch_bounds__(256) void gine64s_kernel(
    const int* __restrict__ rowptr, const int* __restrict__ eid_s,
    const int* __restrict__ src, const float* __restrict__ ea,
    const float* __restrict__ xin, const float* __restrict__ elw,
    const float* __restrict__ elb, const float* __restrict__ w1,
    const float* __restrict__ b1, const float* __restrict__ eps_p,
    float* __restrict__ tbuf, float* __restrict__ stats) {
  __shared__ float wl[64 * 64];
  __shared__ float hb[4][64];
  __shared__ float red[256];
  int tid = threadIdx.x, lane = tid & 63, wv = tid >> 6;
  for (int i = tid; i < 64 * 64; i += 256) wl[i] = w1[i];
  float wel[7];
#pragma unroll
  for (int k = 0; k < 7; k++) wel[k] = elw[k * 64 + lane];
  float bel = elb[lane], b1c = b1[lane];
  float ep = 1.0f + *eps_p;
  float s = 0.f, ss = 0.f;
  __syncthreads();
  int nw = gridDim.x * 4;
  for (int n = blockIdx.x * 4 + wv; n < NN; n += nw) {
    int r0 = rowptr[n], r1 = rowptr[n + 1];
    float acc = 0.f;
    for (int i = r0; i < r1; i++) {
      int e = eid_s[i];
      int sn = src[e];
      float m = bel;
#pragma unroll
      for (int k = 0; k < 7; k++) m = fmaf(ea[e * 7 + k], wel[k], m);
      m += xin[sn * 64 + lane];
      acc += fmaxf(m, 0.f);
    }
    float h = ep * xin[n * 64 + lane] + acc;
    hb[wv][lane] = h;
    float t = b1c;
#pragma unroll
    for (int k = 0; k < 64; k++) t = fmaf(hb[wv][k], wl[k * 64 + lane], t);
    tbuf[n * 64 + lane] = t;
    s += t;
    ss += t * t;
  }
  double* dsum = (double*)stats;
  red[tid] = s;
  __syncthreads();
  if (tid < 64) unsafeAtomicAdd(&dsum[tid], (double)(red[tid] + red[tid + 64] + red[tid + 128] + red[tid + 192]));
  __syncthreads();
  red[tid] = ss;
  __syncthreads();
  if (tid < 64) unsafeAtomicAdd(&dsum[64 + tid], (double)(red[tid] + red[tid + 64] + red[tid + 128] + red[tid + 192]));
}

// ===================== legacy (fallback tier B) kernels ======================
__global__ __launch_bounds__(256) void edge1_kernel(
    const float* __restrict__ x, const float* __restrict__ ea,
    const int* __restrict__ src, const int* __restrict__ dst,
    const float* __restrict__ elw, const float* __restrict__ elb,
    float* __restrict__ agg) {
  float w0[7], w1[7];
#pragma unroll
  for (int k = 0; k < 7; k++) { w0[k] = elw[k * 2]; w1[k] = elw[k * 2 + 1]; }
  float b0 = elb[0], b1 = elb[1];
  int stride = gridDim.x * 256;
  for (int e = blockIdx.x * 256 + threadIdx.x; e < NE; e += stride) {
    int s = src[e], d = dst[e];
    float m0 = b0, m1 = b1;
#pragma unroll
    for (int k = 0; k < 7; k++) {
      float a = ea[e * 7 + k];
      m0 = fmaf(a, w0[k], m0);
      m1 = fmaf(a, w1[k], m1);
    }
    m0 = fmaxf(m0 + x[s * 2 + 0], 0.f);
    m1 = fmaxf(m1 + x[s * 2 + 1], 0.f);
    unsafeAtomicAdd(&agg[d * 2 + 0], m0);
    unsafeAtomicAdd(&agg[d * 2 + 1], m1);
  }
}

__global__ __launch_bounds__(256) void edge64_kernel(
    const float* __restrict__ xin, const float* __restrict__ ea,
    const int* __restrict__ src, const int* __restrict__ dst,
    const float* __restrict__ elw, const float* __restrict__ elb,
    float* __restrict__ agg) {
  int lane = threadIdx.x & 63;
  int wid = (blockIdx.x * 256 + threadIdx.x) >> 6;
  int nw = (gridDim.x * 256) >> 6;
  float w[7];
#pragma unroll
  for (int k = 0; k < 7; k++) w[k] = elw[k * 64 + lane];
  float b = elb[lane];
  for (int e = wid; e < NE; e += nw) {
    int eu = __builtin_amdgcn_readfirstlane(e);
    int s = src[eu];
    int d = dst[eu];
    float m = b;
#pragma unroll
    for (int k = 0; k < 7; k++) m = fmaf(ea[eu * 7 + k], w[k], m);
    m += xin[s * 64 + lane];
    m = fmaxf(m, 0.f);
    unsafeAtomicAdd(&agg[d * 64 + lane], m);
  }
}

__global__ __launch_bounds__(256) void nodeA64_kernel(
    const float* __restrict__ xin, float* __restrict__ tbuf,
    const float* __restrict__ w1, const float* __restrict__ b1,
    const float* __restrict__ eps_p, float* __restrict__ stats) {
  __shared__ float wl[64 * 64];
  __shared__ float hbuf[4][64];
  __shared__ float red[256];
  int tid = threadIdx.x;
  int c = tid & 63, nl = tid >> 6;
  for (int i = tid; i < 64 * 64; i += 256) wl[i] = w1[i];
  float ep = 1.0f + *eps_p;
  float bc = b1[c];
  float s = 0.f, ss = 0.f;
  __syncthreads();
  for (int n0 = blockIdx.x * 4; n0 < NN; n0 += gridDim.x * 4) {
    int n = n0 + nl;
    bool valid = n < NN;
    float h = 0.f;
    if (valid) h = ep * xin[n * 64 + c] + tbuf[n * 64 + c];
    hbuf[nl][c] = h;
    __syncthreads();
    if (valid) {
      float t = bc;
#pragma unroll
      for (int k = 0; k < 64; k++) t = fmaf(hbuf[nl][k], wl[k * 64 + c], t);
      tbuf[n * 64 + c] = t;
      s += t;
      ss += t * t;
    }
    __syncthreads();
  }
  double* dsum = (double*)stats;
  red[tid] = s;
  __syncthreads();
  if (tid < 64) unsafeAtomicAdd(&dsum[tid], (double)(red[tid] + red[tid + 64] + red[tid + 128] + red[tid + 192]));
  __syncthreads();
  red[tid] = ss;
  __syncthreads();
  if (tid < 64) unsafeAtomicAdd(&dsum[64 + tid], (double)(red[tid] + red[tid + 64] + red[tid + 128] + red[tid + 192]));
}

// ===================== shared node kernels ===================================
__global__ __launch_bounds__(256) void nodeA2_kernel(
    const float* __restrict__ x, const float* __restrict__ agg1,
    float* __restrict__ tbuf, const float* __restrict__ w1,
    const float* __restrict__ b1, const float* __restrict__ eps_p,
    float* __restrict__ stats) {
  __shared__ float red[256];
  int tid = threadIdx.x;
  int c = tid & 63, nl = tid >> 6;
  float wa = w1[c], wb = w1[64 + c], bc = b1[c];
  float ep = 1.0f + *eps_p;
  float s = 0.f, ss = 0.f;
  for (int n0 = blockIdx.x * 4; n0 < NN; n0 += gridDim.x * 4) {
    int n = n0 + nl;
    if (n < NN) {
      float h0 = ep * x[n * 2 + 0] + agg1[n * 2 + 0];
      float h1 = ep * x[n * 2 + 1] + agg1[n * 2 + 1];
      float t = fmaf(h1, wb, fmaf(h0, wa, bc));
      tbuf[n * 64 + c] = t;
      s += t;
      ss += t * t;
    }
  }
  double* dsum = (double*)stats;
  red[tid] = s;
  __syncthreads();
  if (tid < 64) unsafeAtomicAdd(&dsum[tid], (double)(red[tid] + red[tid + 64] + red[tid + 128] + red[tid + 192]));
  __syncthreads();
  red[tid] = ss;
  __syncthreads();
  if (tid < 64) unsafeAtomicAdd(&dsum[64 + tid], (double)(red[tid] + red[tid + 64] + red[tid + 128] + red[tid + 192]));
}

// --- node B with fused BN finalize: u=relu(BN(t)); out=relu(u@w2+b2)
// --- optionally emits fp16 copy of out (for next layer's gathers)
__global__ __launch_bounds__(256) void nodeB_kernel(
    const float* __restrict__ tin, float* __restrict__ outb,
    const float* __restrict__ w2, const float* __restrict__ b2,
    const float* __restrict__ stats, const float* __restrict__ g,
    const float* __restrict__ bt, unsigned short* __restrict__ xh) {
  __shared__ float wl[64 * 64];
  __shared__ float ubuf[4][64];
  __shared__ float scsh[128];
  int tid = threadIdx.x;
  int c = tid & 63, nl = tid >> 6;
  for (int i = tid; i < 64 * 64; i += 256) wl[i] = w2[i];
  if (tid < 64) {
    const double* ds = (const double*)stats;
    double m = ds[tid] / (double)NN;
    double v = ds[64 + tid] / (double)NN - m * m;
    float sc = g[tid] * (float)(1.0 / sqrt(v + 1e-5));
    scsh[tid] = sc;
    scsh[64 + tid] = bt[tid] - (float)m * sc;
  }
  float bc = b2[c];
  __syncthreads();
  float scale = scsh[c], shift = scsh[64 + c];
  for (int n0 = blockIdx.x * 4; n0 < NN; n0 += gridDim.x * 4) {
    int n = n0 + nl;
    bool valid = n < NN;
    float u = 0.f;
    if (valid) {
      float t = tin[n * 64 + c];
      u = fmaxf(fmaf(t, scale, shift), 0.f);
    }
    ubuf[nl][c] = u;
    __syncthreads();
    if (valid) {
      float o = bc;
#pragma unroll
      for (int k = 0; k < 64; k++) o = fmaf(ubuf[nl][k], wl[k * 64 + c], o);
      o = fmaxf(o, 0.f);
      outb[n * 64 + c] = o;
      if (xh) xh[n * 64 + c] = f1h(o);
    }
    __syncthreads();
  }
}

__global__ __launch_bounds__(256) void final_kernel(
    const float* __restrict__ xin, const float* __restrict__ regw,
    const float* __restrict__ regb, const float* __restrict__ endw,
    const float* __restrict__ endb, float* __restrict__ out) {
  __shared__ float wl[64 * 128];
  __shared__ float eb[256];
  int tid = threadIdx.x;
  int node = blockIdx.x * 256 + tid;
  bool valid = node < NN;
  float xr[64];
  if (valid) {
    const float4* xp = (const float4*)(xin + node * 64);
#pragma unroll
    for (int k4 = 0; k4 < 16; k4++) {
      float4 v = xp[k4];
      xr[k4 * 4 + 0] = v.x; xr[k4 * 4 + 1] = v.y;
      xr[k4 * 4 + 2] = v.z; xr[k4 * 4 + 3] = v.w;
    }
  }
  float y = 0.f;
  for (int ch = 0; ch < 4; ch++) {
    int j0 = ch * 125;
    __syncthreads();
    for (int idx = tid; idx < 64 * 125; idx += 256) {
      int k = idx / 125;
      int jl = idx - k * 125;
      wl[k * 128 + jl] = regw[k * 500 + j0 + jl];
    }
    if (tid < 125) { eb[tid] = regb[j0 + tid]; eb[128 + tid] = endw[j0 + tid]; }
    __syncthreads();
    if (valid) {
      int jl = 0;
      for (; jl + 4 <= 125; jl += 4) {
        float t0 = eb[jl], t1 = eb[jl + 1], t2 = eb[jl + 2], t3 = eb[jl + 3];
#pragma unroll
        for (int k = 0; k < 64; k++) {
          float4 w4 = *(const float4*)&wl[k * 128 + jl];
          float xv = xr[k];
          t0 = fmaf(xv, w4.x, t0);
          t1 = fmaf(xv, w4.y, t1);
          t2 = fmaf(xv, w4.z, t2);
          t3 = fmaf(xv, w4.w, t3);
        }
        t0 = t0 >= 0.f ? t0 : 0.01f * t0;
        t1 = t1 >= 0.f ? t1 : 0.01f * t1;
        t2 = t2 >= 0.f ? t2 : 0.01f * t2;
        t3 = t3 >= 0.f ? t3 : 0.01f * t3;
        y += t0 * eb[128 + jl] + t1 * eb[128 + jl + 1] + t2 * eb[128 + jl + 2] + t3 * eb[128 + jl + 3];
      }
      {
        float t = eb[124];
#pragma unroll
        for (int k = 0; k < 64; k++) t = fmaf(xr[k], wl[k * 128 + 124], t);
        t = t >= 0.f ? t : 0.01f * t;
        y += t * eb[128 + 124];
      }
    }
  }
  if (valid) out[node] = y + endb[0];
}

extern "C" void kernel_launch(void* const* d_in, const int* in_sizes, int n_in,
                              void* d_out, int out_size, void* d_ws, size_t ws_size,
                              hipStream_t stream) {
  const float* x    = (const float*)d_in[0];
  const float* ea   = (const float*)d_in[1];
  const int*   ei   = (const int*)d_in[2];
  const float* eps1 = (const float*)d_in[4];
  const float* el1w = (const float*)d_in[5];
  const float* el1b = (const float*)d_in[6];
  const float* n1w1 = (const float*)d_in[7];
  const float* n1b1 = (const float*)d_in[8];
  const float* n1g  = (const float*)d_in[9];
  const float* n1bt = (const float*)d_in[10];
  const float* n1w2 = (const float*)d_in[11];
  const float* n1b2 = (const float*)d_in[12];
  const float* eps2 = (const float*)d_in[13];
  const float* el2w = (const float*)d_in[14];
  const float* el2b = (const float*)d_in[15];
  const float* n2w1 = (const float*)d_in[16];
  const float* n2b1 = (const float*)d_in[17];
  const float* n2g  = (const float*)d_in[18];
  const float* n2bt = (const float*)d_in[19];
  const float* n2w2 = (const float*)d_in[20];
  const float* n2b2 = (const float*)d_in[21];
  const float* regw = (const float*)d_in[22];
  const float* regb = (const float*)d_in[23];
  const float* endw = (const float*)d_in[24];
  const float* endb = (const float*)d_in[25];
  const int* srcp = ei;
  const int* dstp = ei + NE;

  // ---- tier-A layout (float offsets) ----
  const size_t o_stats  = 0;          // 768 floats = 3 layers × 128 doubles
  const size_t o_cnt    = 768;        // NN ints (contiguous w/ stats: one memset)
  const size_t o_rowptr = 100768;     // NN+1 ints
  const size_t o_buf0   = 200832;     // N*64 floats; msg1 [E]float2 pre-layer-2
  const size_t o_buf1   = 6600832;    // N*64 floats
  const size_t o_xh     = 13000832;   // N*64 fp16 (= 3.2M floats)
  const size_t o_agg1   = 16200832;   // N*2 floats
  const size_t o_edat   = 16400832;   // packed: E uint4 | slim: E ints
  const size_t o_srcs   = 29200832;   // E ints (packed tier)
  const size_t needA2 = (o_srcs + (size_t)NE) * 4;  // ~129.6 MB
  const size_t needA1 = (o_edat + (size_t)NE) * 4;  // ~78.4 MB
  const size_t needB  = (2 * 6600000 + 384) * 4;    // ~52.8 MB

  float* wsf = (float*)d_ws;

  if (ws_size >= needA1) {
    const bool packed = ws_size >= needA2;
    float* stats0 = wsf + o_stats;        // layer 1
    float* stats1 = wsf + o_stats + 256;  // layer 2
    float* stats2 = wsf + o_stats + 512;  // layer 3
    int* cnt     = (int*)(wsf + o_cnt);
    int* rowptr  = (int*)(wsf + o_rowptr);
    float* buf0  = wsf + o_buf0;
    float* buf1  = wsf + o_buf1;
    unsigned short* xh = (unsigned short*)(wsf + o_xh);
    float* agg1  = wsf + o_agg1;
    uint4* erec  = (uint4*)(wsf + o_edat);
    int* esrc    = (int*)(wsf + o_srcs);
    float* msg1  = buf0;  // [E]float2 == N*64 floats exactly; free until layer 2

    // ---- one memset covers stats(3 layers) + cnt ----
    hipMemsetAsync(wsf, 0, (768 + NN) * sizeof(float), stream);

    // ---- CSR build (once, shared by all 3 layers) ----
    count_kernel<<<4096, 256, 0, stream>>>(dstp, cnt);
    scan_kernel<<<1, 1024, 0, stream>>>(cnt, rowptr, cnt);
    if (packed)
      scatter2h_kernel<<<4096, 256, 0, stream>>>(srcp, dstp, ea, cnt, erec, esrc,
                                                 x, el1w, el1b, msg1);
    else
      scatter1_kernel<<<4096, 256, 0, stream>>>(dstp, cnt, (int*)(wsf + o_edat));

    // ---- layer 1 ----
    if (packed)
      l1sum_kernel<<<391, 256, 0, stream>>>(rowptr, msg1, agg1);
    else
      l1agg_kernel<<<391, 256, 0, stream>>>(rowptr, (const int*)(wsf + o_edat),
                                            srcp, ea, x, el1w, el1b, agg1);
    nodeA2_kernel<<<2048, 256, 0, stream>>>(x, agg1, buf1, n1w1, n1b1, eps1, stats0);
    nodeB_kernel<<<2048, 256, 0, stream>>>(buf1, buf1, n1w2, n1b2, stats0,
                                           n1g, n1bt, packed ? xh : nullptr);

    // ---- layers 2,3 (shared weights) ----
    if (packed) {
      gine64h_kernel<<<4096, 256, 0, stream>>>(rowptr, erec, esrc, buf1, xh,
                                               el2w, el2b, n2w1, n2b1, eps2,
                                               buf0, stats1);
      nodeB_kernel<<<2048, 256, 0, stream>>>(buf0, buf0, n2w2, n2b2, stats1,
                                             n2g, n2bt, xh);
      gine64h_kernel<<<4096, 256, 0, stream>>>(rowptr, erec, esrc, buf0, xh,
                                               el2w, el2b, n2w1, n2b1, eps2,
                                               buf1, stats2);
      nodeB_kernel<<<2048, 256, 0, stream>>>(buf1, buf1, n2w2, n2b2, stats2,
                                             n2g, n2bt, nullptr);
      final_kernel<<<(NN + 255) / 256, 256, 0, stream>>>(buf1, regw, regb, endw,
                                                         endb, (float*)d_out);
    } else {
      float* cur = buf1;
      float* wrk = buf0;
      float* sl[2] = {stats1, stats2};
      for (int l = 0; l < 2; l++) {
        gine64s_kernel<<<4096, 256, 0, stream>>>(rowptr, (const int*)(wsf + o_edat),
                                                 srcp, ea, cur, el2w, el2b, n2w1,
                                                 n2b1, eps2, wrk, sl[l]);
        nodeB_kernel<<<2048, 256, 0, stream>>>(wrk, wrk, n2w2, n2b2, sl[l],
                                               n2g, n2bt, nullptr);
        float* tmp = cur; cur = wrk; wrk = tmp;
      }
      final_kernel<<<(NN + 255) / 256, 256, 0, stream>>>(cur, regw, regb, endw,
                                                         endb, (float*)d_out);
    }
    return;
  }

  // ================= fallback tier B (round-1 proven path) =================
  if (ws_size < needB) return;
  const size_t BUF = 6600000;
  float* buf0 = (float*)d_ws;
  float* buf1 = buf0 + BUF;
  float* stats = buf1 + BUF;

  float* t1 = buf1;
  float* agg1 = buf1 + NN * 64;
  hipMemsetAsync(agg1, 0, NN * 2 * sizeof(float), stream);
  hipMemsetAsync(stats, 0, 128 * sizeof(double), stream);
  edge1_kernel<<<2048, 256, 0, stream>>>(x, ea, srcp, dstp, el1w, el1b, agg1);
  nodeA2_kernel<<<2048, 256, 0, stream>>>(x, agg1, t1, n1w1, n1b1, eps1, stats);
  nodeB_kernel<<<2048, 256, 0, stream>>>(t1, buf1, n1w2, n1b2, stats, n1g, n1bt,
                                         nullptr);

  float* cur = buf1;
  float* wrk = buf0;
  for (int l = 0; l < 2; l++) {
    hipMemsetAsync(wrk, 0, NN * 64 * sizeof(float), stream);
    hipMemsetAsync(stats, 0, 128 * sizeof(double), stream);
    edge64_kernel<<<2048, 256, 0, stream>>>(cur, ea, srcp, dstp, el2w, el2b, wrk);
    nodeA64_kernel<<<2048, 256, 0, stream>>>(cur, wrk, n2w1, n2b1, eps2, stats);
    nodeB_kernel<<<2048, 256, 0, stream>>>(wrk, wrk, n2w2, n2b2, stats, n2g, n2bt,
                                           nullptr);
    float* tmp = cur; cur = wrk; wrk = tmp;
  }

  final_kernel<<<(NN + 255) / 256, 256, 0, stream>>>(cur, regw, regb, endw, endb,
                                                     (float*)d_out);
}